// Round 1
// baseline (240.173 us; speedup 1.0000x reference)
//
#include <hip/hip_runtime.h>
#include <stdint.h>

typedef __attribute__((ext_vector_type(8))) short short8;
typedef __attribute__((ext_vector_type(4))) float floatx4;
typedef __attribute__((ext_vector_type(16))) float floatx16;
typedef __attribute__((ext_vector_type(4))) unsigned int uintx4;
typedef unsigned short u16;
typedef unsigned int u32;

#define EDIM 128
#define FDIM 512

// round-to-nearest-even float -> bf16 (prep path)
__device__ __forceinline__ u32 f2bf_rne(float f) {
    u32 u = __builtin_bit_cast(u32, f);
    return (u + 0x7fffu + ((u >> 16) & 1u)) >> 16;
}
__device__ __forceinline__ u32 pk2bf(float lo, float hi) {
    return f2bf_rne(lo) | (f2bf_rne(hi) << 16);
}
// HW packed f32x2 -> bf16x2, RNE (main path)
__device__ __forceinline__ u32 cvtpk(float lo, float hi) {
    u32 r;
    asm("v_cvt_pk_bf16_f32 %0, %1, %2" : "=v"(r) : "v"(lo), "v"(hi));
    return r;
}
// swap upper 32 lanes of a with lower 32 lanes of b
__device__ __forceinline__ void plswap(u32& a, u32& b) {
    asm("v_permlane32_swap_b32 %0, %1" : "+v"(a), "+v"(b));
}

// Pre-swizzle W1/W2 to bf16 in MFMA A-fragment lane order (unchanged layout):
//   W1s group g  = tile*512 + k*64 + lane   (16B per group)
//        holds W1[tile*32 + (lane&31)][k*16 + (lane>>5)*8 + j], j=0..7
//   W2s group g2 = (et*4+c)*512 + k*64 + lane
//        holds W2[et*32 + (lane&31)][c*128 + k*16 + (lane>>5)*8 + j]
// Also: cth[e] = cos(theta[e]) as f32 at wb + 2*FDIM*EDIM (u16 offset).
__global__ __launch_bounds__(256) void ffq_prep(const float* __restrict__ W1,
                                                const float* __restrict__ W2,
                                                const float* __restrict__ theta,
                                                u16* __restrict__ wb) {
    int g = blockIdx.x * 256 + threadIdx.x;   // 0..16383
    int lane = g & 63;
    int kk = (g >> 6) & 7;
    int idx = (g >> 9) & 15;
    int l31 = lane & 31, h5 = lane >> 5;
    if (g < 128) {
        float* cth = reinterpret_cast<float*>(wb + 2 * FDIM * EDIM);
        cth[g] = cosf(theta[g]);
    }
    const float* src;
    if (g < 8192) {
        src = W1 + (idx * 32 + l31) * EDIM + kk * 16 + h5 * 8;
    } else {
        int gg = idx >> 2, c = idx & 3;
        src = W2 + (gg * 32 + l31) * FDIM + c * 128 + kk * 16 + h5 * 8;
    }
    float4 v0 = *reinterpret_cast<const float4*>(src);
    float4 v1 = *reinterpret_cast<const float4*>(src + 4);
    uint4 p;
    p.x = pk2bf(v0.x, v0.y);
    p.y = pk2bf(v0.z, v0.w);
    p.z = pk2bf(v1.x, v1.y);
    p.w = pk2bf(v1.z, v1.w);
    reinterpret_cast<uint4*>(wb)[g] = p;
}

// Fused q = cos(x)*cos(theta); h = relu(q@W1^T); out = h@W2^T.
// One wave owns 32 token rows end-to-end. h never leaves registers:
// GEMM1 D-layout -> (relu, cvt_pk_bf16, permlane32_swap) -> GEMM2 B-frags.
// No LDS, no __syncthreads.
__global__ __launch_bounds__(256, 3) void ffq_main(const float* __restrict__ x,
                                                   const u16* __restrict__ wb,
                                                   float* __restrict__ out) {
    const int t = threadIdx.x;
    const int lane = t & 63;
    const int l31 = lane & 31;
    const int h5 = lane >> 5;
    const int gw = blockIdx.x * 4 + (t >> 6);   // global wave id, 0..4095
    const size_t row0 = (size_t)gw * 32;        // rows row0..row0+31

    const u16* W1s = wb;
    const u16* W2s = wb + FDIM * EDIM;
    const float* cth = reinterpret_cast<const float*>(wb + 2 * FDIM * EDIM);

    // ---- stage q fragments straight into registers (B-frag layout) ----
    // qf[k] element j = q[row0 + l31][e = k*16 + h5*8 + j]
    short8 qf[8];
    {
        const float* xr = x + (row0 + l31) * EDIM + h5 * 8;
        const float* tr = cth + h5 * 8;
        #pragma unroll
        for (int k = 0; k < 8; ++k) {
            float4 x0 = *reinterpret_cast<const float4*>(xr + k * 16);
            float4 x1 = *reinterpret_cast<const float4*>(xr + k * 16 + 4);
            float4 t0 = *reinterpret_cast<const float4*>(tr + k * 16);
            float4 t1 = *reinterpret_cast<const float4*>(tr + k * 16 + 4);
            uintx4 u;
            u[0] = cvtpk(__cosf(x0.x) * t0.x, __cosf(x0.y) * t0.y);
            u[1] = cvtpk(__cosf(x0.z) * t0.z, __cosf(x0.w) * t0.w);
            u[2] = cvtpk(__cosf(x1.x) * t1.x, __cosf(x1.y) * t1.y);
            u[3] = cvtpk(__cosf(x1.z) * t1.z, __cosf(x1.w) * t1.w);
            qf[k] = __builtin_bit_cast(short8, u);
        }
    }

    const floatx16 zero = {0.f,0.f,0.f,0.f,0.f,0.f,0.f,0.f,
                           0.f,0.f,0.f,0.f,0.f,0.f,0.f,0.f};
    floatx16 acc[4] = {zero, zero, zero, zero};  // out^T e-tiles 0..3

    const u16* w1l = W1s + lane * 8;
    const u16* w2l = W2s + lane * 8;

    for (int c = 0; c < 4; ++c) {          // f-chunk of 128
        #pragma unroll
        for (int f4 = 0; f4 < 4; ++f4) {   // f-tile within chunk
            // ---- GEMM1: h^T f-tile (32f x 32m) = W1_tile x q^T, K = 128 ----
            floatx16 a1 = zero;
            const u16* w1p = w1l + (c * 4 + f4) * 4096;
            #pragma unroll
            for (int k = 0; k < 8; ++k) {
                short8 a = *reinterpret_cast<const short8*>(w1p + k * 512);
                a1 = __builtin_amdgcn_mfma_f32_32x32x16_bf16(a, qf[k], a1, 0, 0, 0);
            }
            // ---- relu + bf16 pack: quad q covers f = 8q + 4h5 + {0..3} ----
            u32 w[8];
            #pragma unroll
            for (int q = 0; q < 4; ++q) {
                w[2*q]   = cvtpk(fmaxf(a1[4*q+0], 0.f), fmaxf(a1[4*q+1], 0.f));
                w[2*q+1] = cvtpk(fmaxf(a1[4*q+2], 0.f), fmaxf(a1[4*q+3], 0.f));
            }
            // ---- half-wave f-quad exchange -> GEMM2 B-frags in-place ----
            plswap(w[0], w[2]);   // ks=0: words 0,2
            plswap(w[1], w[3]);   // ks=0: words 1,3
            plswap(w[4], w[6]);   // ks=1: words 0,2
            plswap(w[5], w[7]);   // ks=1: words 1,3
            uintx4 u0, u1;
            u0[0] = w[0]; u0[1] = w[1]; u0[2] = w[2]; u0[3] = w[3];
            u1[0] = w[4]; u1[1] = w[5]; u1[2] = w[6]; u1[3] = w[7];
            short8 hb0 = __builtin_bit_cast(short8, u0);
            short8 hb1 = __builtin_bit_cast(short8, u1);
            // ---- GEMM2: accumulate 4 e-tiles, this f-tile's K = 32 ----
            #pragma unroll
            for (int et = 0; et < 4; ++et) {
                const u16* w2p = w2l + (et * 4 + c) * 4096 + f4 * 1024;
                short8 b0 = *reinterpret_cast<const short8*>(w2p);
                acc[et] = __builtin_amdgcn_mfma_f32_32x32x16_bf16(b0, hb0, acc[et], 0, 0, 0);
                short8 b1 = *reinterpret_cast<const short8*>(w2p + 512);
                acc[et] = __builtin_amdgcn_mfma_f32_32x32x16_bf16(b1, hb1, acc[et], 0, 0, 0);
            }
        }
    }

    // ---- epilogue: D col m=l31, row e = et*32 + (r&3) + 8*(r>>2) + 4*h5 ----
    float* op = out + (row0 + l31) * EDIM + h5 * 4;
    #pragma unroll
    for (int et = 0; et < 4; ++et) {
        #pragma unroll
        for (int rq = 0; rq < 4; ++rq) {
            floatx4 v;
            v[0] = acc[et][rq * 4 + 0];
            v[1] = acc[et][rq * 4 + 1];
            v[2] = acc[et][rq * 4 + 2];
            v[3] = acc[et][rq * 4 + 3];
            *reinterpret_cast<floatx4*>(op + et * 32 + rq * 8) = v;
        }
    }
}

extern "C" void kernel_launch(void* const* d_in, const int* in_sizes, int n_in,
                              void* d_out, int out_size, void* d_ws, size_t ws_size,
                              hipStream_t stream) {
    const float* x     = (const float*)d_in[0];  // [32,4096,128]
    const float* theta = (const float*)d_in[1];  // [128]
    const float* W1    = (const float*)d_in[2];  // [512,128]
    const float* W2    = (const float*)d_in[3];  // [128,512]
    u16* wb    = (u16*)d_ws;                     // 256 KB bf16 weights + 512 B cos(theta)
    float* out = (float*)d_out;                  // [32,4096,128]

    ffq_prep<<<64, 256, 0, stream>>>(W1, W2, theta, wb);
    ffq_main<<<1024, 256, 0, stream>>>(x, wb, out);
}

// Round 2
// 185.471 us; speedup vs baseline: 1.2949x; 1.2949x over previous
//
#include <hip/hip_runtime.h>
#include <stdint.h>

typedef __attribute__((ext_vector_type(8))) short short8;
typedef __attribute__((ext_vector_type(4))) float floatx4;
typedef __attribute__((ext_vector_type(16))) float floatx16;
typedef __attribute__((ext_vector_type(2))) unsigned int uintx2;
typedef __attribute__((ext_vector_type(4))) unsigned int uintx4;
typedef unsigned short u16;
typedef unsigned int u32;

#define EDIM 128
#define FDIM 512
#define BM 128
#define QSTR 136   // bf16 row stride (272 B, 16B-aligned)

// round-to-nearest-even float -> bf16 (prep path)
__device__ __forceinline__ u32 f2bf_rne(float f) {
    u32 u = __builtin_bit_cast(u32, f);
    return (u + 0x7fffu + ((u >> 16) & 1u)) >> 16;
}
__device__ __forceinline__ u32 pk2bf(float lo, float hi) {
    return f2bf_rne(lo) | (f2bf_rne(hi) << 16);
}
// HW packed f32x2 -> bf16x2, RNE (main path)
__device__ __forceinline__ u32 cvtpk(float lo, float hi) {
    u32 r;
    asm("v_cvt_pk_bf16_f32 %0, %1, %2" : "=v"(r) : "v"(lo), "v"(hi));
    return r;
}
// swap upper 32 lanes of a with lower 32 lanes of b
__device__ __forceinline__ void plswap(u32& a, u32& b) {
    asm("v_permlane32_swap_b32 %0, %1" : "+v"(a), "+v"(b));
}

// Pre-swizzle W1/W2 to bf16 in MFMA A-fragment lane order:
//   W1s group g  = ft*512 + k*64 + lane   (16B per group)
//        holds W1[ft*32 + (lane&31)][k*16 + (lane>>5)*8 + j], j=0..7
//   W2s group g2 = (et*4+c)*512 + k*64 + lane
//        holds W2[et*32 + (lane&31)][c*128 + k*16 + (lane>>5)*8 + j]
// Also: cth[e] = cos(theta[e]) as f32 at wb + 2*FDIM*EDIM (u16 offset).
__global__ __launch_bounds__(256) void ffq_prep(const float* __restrict__ W1,
                                                const float* __restrict__ W2,
                                                const float* __restrict__ theta,
                                                u16* __restrict__ wb) {
    int g = blockIdx.x * 256 + threadIdx.x;   // 0..16383
    int lane = g & 63;
    int kk = (g >> 6) & 7;
    int idx = (g >> 9) & 15;
    int l31 = lane & 31, h5 = lane >> 5;
    if (g < 128) {
        float* cth = reinterpret_cast<float*>(wb + 2 * FDIM * EDIM);
        cth[g] = cosf(theta[g]);
    }
    const float* src;
    if (g < 8192) {
        src = W1 + (idx * 32 + l31) * EDIM + kk * 16 + h5 * 8;
    } else {
        int gg = idx >> 2, c = idx & 3;
        src = W2 + (gg * 32 + l31) * FDIM + c * 128 + kk * 16 + h5 * 8;
    }
    float4 v0 = *reinterpret_cast<const float4*>(src);
    float4 v1 = *reinterpret_cast<const float4*>(src + 4);
    uint4 p;
    p.x = pk2bf(v0.x, v0.y);
    p.y = pk2bf(v0.z, v0.w);
    p.z = pk2bf(v1.x, v1.y);
    p.w = pk2bf(v1.z, v1.w);
    reinterpret_cast<uint4*>(wb)[g] = p;
}

// Fused q = cos(x)*cos(theta); h = relu(q@W1^T); out = h@W2^T.
// 128 rows/block, 8 waves = 4 m-groups x 2 f-halves.
// Each wave: 32 rows x 128 e partial over its 256-f half, h in registers
// (GEMM1 D -> relu/cvt_pk/permlane32_swap -> GEMM2 B-frags). No barriers in
// the MFMA loop; one 2-way f32 reduction through LDS at the end.
__global__ __launch_bounds__(512, 4) void ffq_main(const float* __restrict__ x,
                                                   const u16* __restrict__ wb,
                                                   float* __restrict__ out) {
    __shared__ u16 qs[BM * QSTR];     // 34816 B
    __shared__ float red[8 * 1024];   // 32768 B reduction buffer

    const int t = threadIdx.x;
    const int lane = t & 63;
    const int wv = t >> 6;        // 0..7
    const int l31 = lane & 31;
    const int h5 = lane >> 5;
    const int fg = wv & 1;        // f-half 0/1
    const int mg = wv >> 1;       // m-group 0..3 (rows mg*32..+31)

    const u16* W1s = wb;
    const u16* W2s = wb + FDIM * EDIM;
    const float* cth = reinterpret_cast<const float*>(wb + 2 * FDIM * EDIM);

    // ---- stage q = cos(x)*cos(theta) into LDS (bf16), coalesced ----
    {
        const float4* xin = reinterpret_cast<const float4*>(x) +
                            (size_t)blockIdx.x * (BM * EDIM / 4);
        const int et = (t & 31) * 4;  // e offset; same each r since 512 % 32 == 0
        float c0 = cth[et + 0];
        float c1 = cth[et + 1];
        float c2 = cth[et + 2];
        float c3 = cth[et + 3];
        #pragma unroll
        for (int r = 0; r < 8; ++r) {
            int i = t + 512 * r;   // float4 index within tile
            int m = i >> 5;        // row 0..127
            float4 v = xin[i];
            uintx2 p;
            p.x = pk2bf(__cosf(v.x) * c0, __cosf(v.y) * c1);
            p.y = pk2bf(__cosf(v.z) * c2, __cosf(v.w) * c3);
            *reinterpret_cast<uintx2*>(&qs[m * QSTR + et]) = p;
        }
    }
    __syncthreads();

    // ---- q B-fragments into registers once; reused for all 8 f-tiles ----
    // qf[k] element j = q[row0 + l31][e = k*16 + h5*8 + j]
    short8 qf[8];
    {
        const u16* qp = &qs[(mg * 32 + l31) * QSTR + h5 * 8];
        #pragma unroll
        for (int k = 0; k < 8; ++k)
            qf[k] = *reinterpret_cast<const short8*>(qp + k * 16);
    }

    const floatx16 zero = {0.f,0.f,0.f,0.f,0.f,0.f,0.f,0.f,
                           0.f,0.f,0.f,0.f,0.f,0.f,0.f,0.f};
    floatx16 acc[4] = {zero, zero, zero, zero};  // out^T e-tiles (partial over f-half)

    const u16* w1l = W1s + lane * 8;
    const u16* w2l = W2s + lane * 8;

    // ---- barrier-free main loop over this wave's 8 f-tiles ----
    #pragma unroll 2
    for (int ft8 = 0; ft8 < 8; ++ft8) {
        const int ft = fg * 8 + ft8;       // global f-tile 0..15
        // GEMM1: h^T f-tile (32f x 32m) = W1_ft x q^T, K = 128
        floatx16 a1 = zero;
        const u16* w1p = w1l + (size_t)ft * 4096;
        #pragma unroll
        for (int k = 0; k < 8; ++k) {
            short8 a = *reinterpret_cast<const short8*>(w1p + k * 512);
            a1 = __builtin_amdgcn_mfma_f32_32x32x16_bf16(a, qf[k], a1, 0, 0, 0);
        }
        // relu + bf16 pack: quad q covers f_local = 8q + 4h5 + {0..3}
        u32 w[8];
        #pragma unroll
        for (int q = 0; q < 4; ++q) {
            w[2*q]   = cvtpk(fmaxf(a1[4*q+0], 0.f), fmaxf(a1[4*q+1], 0.f));
            w[2*q+1] = cvtpk(fmaxf(a1[4*q+2], 0.f), fmaxf(a1[4*q+3], 0.f));
        }
        // half-wave f-quad exchange -> GEMM2 B-frags in-place
        plswap(w[0], w[2]);
        plswap(w[1], w[3]);
        plswap(w[4], w[6]);
        plswap(w[5], w[7]);
        uintx4 u0, u1;
        u0[0] = w[0]; u0[1] = w[1]; u0[2] = w[2]; u0[3] = w[3];
        u1[0] = w[4]; u1[1] = w[5]; u1[2] = w[6]; u1[3] = w[7];
        short8 hb0 = __builtin_bit_cast(short8, u0);
        short8 hb1 = __builtin_bit_cast(short8, u1);
        // GEMM2: accumulate 4 e-tiles, this f-tile's K = 32
        const int c = ft >> 2, f4 = ft & 3;
        #pragma unroll
        for (int et = 0; et < 4; ++et) {
            const u16* w2p = w2l + (size_t)(et * 4 + c) * 4096 + f4 * 1024;
            short8 b0 = *reinterpret_cast<const short8*>(w2p);
            acc[et] = __builtin_amdgcn_mfma_f32_32x32x16_bf16(b0, hb0, acc[et], 0, 0, 0);
            short8 b1 = *reinterpret_cast<const short8*>(w2p + 512);
            acc[et] = __builtin_amdgcn_mfma_f32_32x32x16_bf16(b1, hb1, acc[et], 0, 0, 0);
        }
    }

    // ---- 2-way f-partial reduction + store ----
    // D layout per tile: col m = l31, row e_local = (reg&3) + 8*(reg>>2) + 4*h5.
    // Conflict-free LDS tiles: 1024 f32 each, lane strides 16 B.
    float* op = out + (size_t)blockIdx.x * BM * EDIM +
                (mg * 32 + l31) * EDIM + h5 * 4;

    if (fg == 1) {   // round A: fg1 publishes e-tiles 0,1
        #pragma unroll
        for (int s = 0; s < 2; ++s) {
            float* rb = &red[(mg * 2 + s) * 1024 + lane * 4];
            #pragma unroll
            for (int q = 0; q < 4; ++q) {
                floatx4 v;
                v[0] = acc[s][q*4+0]; v[1] = acc[s][q*4+1];
                v[2] = acc[s][q*4+2]; v[3] = acc[s][q*4+3];
                *reinterpret_cast<floatx4*>(rb + q * 256) = v;
            }
        }
    }
    __syncthreads();
    if (fg == 0) {   // fg0: finalize e-tiles 0,1; publish 2,3
        #pragma unroll
        for (int s = 0; s < 2; ++s) {
            float* rb = &red[(mg * 2 + s) * 1024 + lane * 4];
            #pragma unroll
            for (int q = 0; q < 4; ++q) {
                floatx4 r = *reinterpret_cast<const floatx4*>(rb + q * 256);
                floatx4 v;
                v[0] = acc[s][q*4+0] + r[0]; v[1] = acc[s][q*4+1] + r[1];
                v[2] = acc[s][q*4+2] + r[2]; v[3] = acc[s][q*4+3] + r[3];
                *reinterpret_cast<floatx4*>(op + s * 32 + q * 8) = v;
            }
        }
        #pragma unroll
        for (int s = 0; s < 2; ++s) {
            float* rb = &red[(mg * 2 + s) * 1024 + lane * 4];
            #pragma unroll
            for (int q = 0; q < 4; ++q) {
                floatx4 v;
                v[0] = acc[2+s][q*4+0]; v[1] = acc[2+s][q*4+1];
                v[2] = acc[2+s][q*4+2]; v[3] = acc[2+s][q*4+3];
                *reinterpret_cast<floatx4*>(rb + q * 256) = v;
            }
        }
    }
    __syncthreads();
    if (fg == 1) {   // fg1: finalize e-tiles 2,3
        #pragma unroll
        for (int s = 0; s < 2; ++s) {
            float* rb = &red[(mg * 2 + s) * 1024 + lane * 4];
            #pragma unroll
            for (int q = 0; q < 4; ++q) {
                floatx4 r = *reinterpret_cast<const floatx4*>(rb + q * 256);
                floatx4 v;
                v[0] = acc[2+s][q*4+0] + r[0]; v[1] = acc[2+s][q*4+1] + r[1];
                v[2] = acc[2+s][q*4+2] + r[2]; v[3] = acc[2+s][q*4+3] + r[3];
                *reinterpret_cast<floatx4*>(op + (2+s) * 32 + q * 8) = v;
            }
        }
    }
}

extern "C" void kernel_launch(void* const* d_in, const int* in_sizes, int n_in,
                              void* d_out, int out_size, void* d_ws, size_t ws_size,
                              hipStream_t stream) {
    const float* x     = (const float*)d_in[0];  // [32,4096,128]
    const float* theta = (const float*)d_in[1];  // [128]
    const float* W1    = (const float*)d_in[2];  // [512,128]
    const float* W2    = (const float*)d_in[3];  // [128,512]
    u16* wb    = (u16*)d_ws;                     // 256 KB bf16 weights + 512 B cos(theta)
    float* out = (float*)d_out;                  // [32,4096,128]

    ffq_prep<<<64, 256, 0, stream>>>(W1, W2, theta, wb);
    ffq_main<<<1024, 512, 0, stream>>>(x, wb, out);
}